// Round 5
// baseline (347.895 us; speedup 1.0000x reference)
//
#include <hip/hip_runtime.h>

// Involution2d fused, R5: R4 + fix (w_span A-frag was missing the quad*8
// K-offset -> every quad read quad-0's fragment).
// Block = (batch, 8-row x 16-col tile), 256 threads / 4 waves, 3 blocks/CU.
// Phase 1: rT[p][o] = bf16(ReLU(BN(w_reduce @ x))) via mfma 16x16x32 bf16;
//          B-frags of rT then hoisted to 64 VGPRs (identical for all groups).
// Phase 2 per group: A-frags straight from global (L2); kernel-gen MFMA with
//          zero LDS reads -> s_w fp32; involution 4px x 2cg per lane, b128 reads.
//          xh halos for group g+1 prefetched into regs during involution(g).

typedef __attribute__((ext_vector_type(8))) short bf16x8;
typedef __attribute__((ext_vector_type(4))) float f32x4;

namespace {
constexpr int Cn = 256, Hn = 64, Wn = 64, HWn = 4096;
constexpr int Gn = 16, CGn = 16, CRn = 64;
constexpr int Kn = 7, PADn = 3, KKn = 49;
constexpr int TH = 8, TW = 16;
constexpr int LD = 72, LDW = 36;      // xT/rT bf16 row stride (64+8 pad) / dwords
constexpr int WLD = 132;              // s_w fp32 row stride (128 px + 4 pad)
constexpr int XROW = 28, XPS = 392;   // xh row / plane stride
constexpr int XH_TOT = 16 * XPS;      // 6272 dwords
constexpr int NXV = 25;               // ceil(6272 / 256) staging regs per thread
}

__device__ __forceinline__ unsigned short bf16rne(float f) {
  unsigned u = __float_as_uint(f);
  u += 0x7fffu + ((u >> 16) & 1u);
  return (unsigned short)(u >> 16);
}
__device__ __forceinline__ unsigned packbf2(float a, float b) {
  return (unsigned)bf16rne(a) | ((unsigned)bf16rne(b) << 16);
}
__device__ __forceinline__ bf16x8 pack8(f32x4 a, f32x4 b) {
  union { bf16x8 v; unsigned u[4]; } r;
  r.u[0] = packbf2(a[0], a[1]); r.u[1] = packbf2(a[2], a[3]);
  r.u[2] = packbf2(b[0], b[1]); r.u[3] = packbf2(b[2], b[3]);
  return r.v;
}

__global__ __launch_bounds__(256, 3) void invol_fused(
    const float* __restrict__ x, const float* __restrict__ w_reduce,
    const float* __restrict__ w_span, const float* __restrict__ bn_gamma,
    const float* __restrict__ bn_beta, const float* __restrict__ bn_mean,
    const float* __restrict__ bn_var, float* __restrict__ out)
{
  __shared__ __align__(16) float s_buf[XH_TOT];     // 25088 B: ph1 xT bf16 / ph2 xh fp32
  __shared__ __align__(16) float s_w[KKn * WLD];    // 25872 B: dynamic kernel fp32

  const int t = threadIdx.x;
  const int lane = t & 63, q = t >> 6;
  const int m16 = lane & 15, quad = lane >> 4;
  const int s = lane >> 5;
  const int slot = lane & 31;
  const int py = slot >> 2, px0 = (slot & 3) * 4;
  const int w0 = blockIdx.x * TW, h0 = blockIdx.y * TH;
  const int b = blockIdx.z;
  const long xbase = (long)b * Cn * HWn;

  // BN constants for this lane's phase-1 D rows (o = q*16 + quad*4 + r)
  float bsc[4], bsh[4];
  {
    int ob = q * 16 + quad * 4;
#pragma unroll
    for (int r = 0; r < 4; ++r) {
      float sc = bn_gamma[ob + r] * rsqrtf(bn_var[ob + r] + 1e-5f);
      bsc[r] = sc;
      bsh[r] = bn_beta[ob + r] - bn_mean[ob + r] * sc;
    }
  }

  // ---------------- Phase 1: rT = bf16(ReLU(BN(w_reduce @ x))) ----------------
  unsigned short* xT = (unsigned short*)s_buf;   // [128 p][72] bf16
  f32x4 pac[8];
#pragma unroll
  for (int pt = 0; pt < 8; ++pt) pac[pt] = (f32x4){0.f, 0.f, 0.f, 0.f};

  for (int cc = 0; cc < Cn; cc += 64) {
    __syncthreads();
#pragma unroll
    for (int it = 0; it < 16; ++it) {            // stage xT (2 channels packed)
      int idx = t + it * 256;
      int pp = idx & 127, cp = idx >> 7;
      const float* gp = x + xbase + (long)(cc + cp * 2) * HWn
                        + (h0 + (pp >> 4)) * Wn + (w0 + (pp & 15));
      ((unsigned*)xT)[pp * LDW + cp] = packbf2(gp[0], gp[HWn]);
    }
    __syncthreads();
#pragma unroll
    for (int ks = 0; ks < 2; ++ks) {
      const float* wrp = w_reduce + (q * 16 + m16) * Cn + cc + ks * 32 + quad * 8;
      f32x4 u0 = *(const f32x4*)wrp, u1 = *(const f32x4*)(wrp + 4);
      bf16x8 af = pack8(u0, u1);                 // A-frag straight from global (L2)
#pragma unroll
      for (int pt = 0; pt < 8; ++pt) {
        bf16x8 bf = *(const bf16x8*)(xT + (pt * 16 + m16) * LD + ks * 32 + quad * 8);
        pac[pt] = __builtin_amdgcn_mfma_f32_16x16x32_bf16(af, bf, pac[pt], 0, 0, 0);
      }
    }
  }
  // epilogue: BN+ReLU -> rT[p][o] bf16 (overwrites xT region)
  __syncthreads();
  unsigned short* rT = (unsigned short*)s_buf;
#pragma unroll
  for (int pt = 0; pt < 8; ++pt) {
    int pp = pt * 16 + m16;
    float v0 = fmaxf(fmaf(pac[pt][0], bsc[0], bsh[0]), 0.f);
    float v1 = fmaxf(fmaf(pac[pt][1], bsc[1], bsh[1]), 0.f);
    float v2 = fmaxf(fmaf(pac[pt][2], bsc[2], bsh[2]), 0.f);
    float v3 = fmaxf(fmaf(pac[pt][3], bsc[3], bsh[3]), 0.f);
    ((unsigned*)rT)[pp * LDW + q * 8 + quad * 2 + 0] = packbf2(v0, v1);
    ((unsigned*)rT)[pp * LDW + q * 8 + quad * 2 + 1] = packbf2(v2, v3);
  }
  __syncthreads();
  // hoist kernel-gen B-frags (identical for all 16 groups) into 64 VGPRs
  bf16x8 bfr[16];
#pragma unroll
  for (int ks = 0; ks < 2; ++ks)
#pragma unroll
    for (int pt = 0; pt < 8; ++pt)
      bfr[ks * 8 + pt] = *(const bf16x8*)(rT + (pt * 16 + m16) * LD + ks * 32 + quad * 8);
  // NOTE: s_buf still holds rT until the first group's top barrier.

  // ---------------- Phase 2 ----------------
  const int cgA = q + 4 * s, cgB = cgA + 8;
  const long opix = (h0 + py) * Wn + (w0 + px0);
  int kA = q * 16 + m16; if (kA > 48) kA = 48;   // clamp (rows >=49 are discarded)

  float xv[NXV];
  // prefetch group 0 halos into registers
  {
    const float* xg = x + xbase;
#pragma unroll
    for (int j = 0; j < NXV; ++j) {
      int idx = t + j * 256;
      float v = 0.f;
      if (idx < XH_TOT) {
        int pl = idx / XPS, rem = idx - pl * XPS;
        int iy = rem / XROW, ix = rem - iy * XROW;
        int gy = h0 + iy - PADn, gx = w0 + ix - PADn;
        if (ix < 22 && (unsigned)gy < (unsigned)Hn && (unsigned)gx < (unsigned)Wn)
          v = xg[(long)pl * HWn + gy * Wn + gx];
      }
      xv[j] = v;
    }
  }

#pragma unroll 1
  for (int g = 0; g < Gn; ++g) {
    // A-frag loads for kernel-gen (L2-resident; issue early).
    // FIX vs R4: include quad*8 K-offset (frag = row kA, cols ks*32+quad*8+0..7)
    const float* wsp = w_span + ((long)g * KKn + kA) * CRn + quad * 8;
    f32x4 wa0 = *(const f32x4*)(wsp);
    f32x4 wa1 = *(const f32x4*)(wsp + 4);
    f32x4 wa2 = *(const f32x4*)(wsp + 32);
    f32x4 wa3 = *(const f32x4*)(wsp + 36);

    __syncthreads();   // prior involution done reading s_buf/s_w
    // commit prefetched halos to LDS
#pragma unroll
    for (int j = 0; j < NXV; ++j) {
      int idx = t + j * 256;
      if (idx < XH_TOT) s_buf[idx] = xv[j];
    }
    // kernel-gen: zero LDS reads (A from global regs, B from VGPRs)
    bf16x8 aw0 = pack8(wa0, wa1);
    bf16x8 aw1 = pack8(wa2, wa3);
    f32x4 wac[8];
#pragma unroll
    for (int pt = 0; pt < 8; ++pt) {
      f32x4 acc = (f32x4){0.f, 0.f, 0.f, 0.f};
      acc = __builtin_amdgcn_mfma_f32_16x16x32_bf16(aw0, bfr[pt], acc, 0, 0, 0);
      acc = __builtin_amdgcn_mfma_f32_16x16x32_bf16(aw1, bfr[8 + pt], acc, 0, 0, 0);
      wac[pt] = acc;
    }
    {
      int kb = q * 16 + quad * 4;
#pragma unroll
      for (int r = 0; r < 4; ++r) {
        if (kb + r < KKn) {
#pragma unroll
          for (int pt = 0; pt < 8; ++pt)
            s_w[(kb + r) * WLD + pt * 16 + m16] = wac[pt][r];
        }
      }
    }
    // prefetch next group's halos (in flight across the involution)
    if (g + 1 < Gn) {
      const float* xg = x + xbase + (long)(g + 1) * CGn * HWn;
#pragma unroll
      for (int j = 0; j < NXV; ++j) {
        int idx = t + j * 256;
        float v = 0.f;
        if (idx < XH_TOT) {
          int pl = idx / XPS, rem = idx - pl * XPS;
          int iy = rem / XROW, ix = rem - iy * XROW;
          int gy = h0 + iy - PADn, gx = w0 + ix - PADn;
          if (ix < 22 && (unsigned)gy < (unsigned)Hn && (unsigned)gx < (unsigned)Wn)
            v = xg[(long)pl * HWn + gy * Wn + gx];
        }
        xv[j] = v;
      }
    }
    __syncthreads();   // xh + s_w ready

    // involution: 4 px/lane sliding window, 2 cg planes
    f32x4 a0 = (f32x4){0.f, 0.f, 0.f, 0.f};
    f32x4 a1 = (f32x4){0.f, 0.f, 0.f, 0.f};
    const float* plA = s_buf + cgA * XPS;
    const float* plB = s_buf + cgB * XPS;
#pragma unroll 1
    for (int i = 0; i < Kn; ++i) {
      f32x4 wr_[7];
#pragma unroll
      for (int jx = 0; jx < Kn; ++jx)
        wr_[jx] = *(const f32x4*)(s_w + (i * Kn + jx) * WLD + py * 16 + px0);
      const float* rA = plA + (py + i) * XROW + px0;
      const float* rB = plB + (py + i) * XROW + px0;
      f32x4 xa0 = *(const f32x4*)rA, xa1 = *(const f32x4*)(rA + 4), xa2 = *(const f32x4*)(rA + 8);
      f32x4 xb0 = *(const f32x4*)rB, xb1 = *(const f32x4*)(rB + 4), xb2 = *(const f32x4*)(rB + 8);
      float xa[12] = {xa0[0], xa0[1], xa0[2], xa0[3], xa1[0], xa1[1], xa1[2], xa1[3],
                      xa2[0], xa2[1], xa2[2], xa2[3]};
      float xb[12] = {xb0[0], xb0[1], xb0[2], xb0[3], xb1[0], xb1[1], xb1[2], xb1[3],
                      xb2[0], xb2[1], xb2[2], xb2[3]};
#pragma unroll
      for (int jx = 0; jx < Kn; ++jx) {
#pragma unroll
        for (int j = 0; j < 4; ++j) {
          a0[j] = fmaf(wr_[jx][j], xa[jx + j], a0[j]);
          a1[j] = fmaf(wr_[jx][j], xb[jx + j], a1[j]);
        }
      }
    }
    float* ob = out + xbase + (long)(g * CGn) * HWn + opix;
    *(f32x4*)(ob + (long)cgA * HWn) = a0;
    *(f32x4*)(ob + (long)cgB * HWn) = a1;
  }
}

extern "C" void kernel_launch(void* const* d_in, const int* in_sizes, int n_in,
                              void* d_out, int out_size, void* d_ws, size_t ws_size,
                              hipStream_t stream) {
  const float* x        = (const float*)d_in[0];
  const float* w_reduce = (const float*)d_in[1];
  const float* w_span   = (const float*)d_in[2];
  const float* bn_gamma = (const float*)d_in[3];
  const float* bn_beta  = (const float*)d_in[4];
  const float* bn_mean  = (const float*)d_in[5];
  const float* bn_var   = (const float*)d_in[6];
  float* outp = (float*)d_out;

  dim3 grid(Wn / TW, Hn / TH, 16);  // 4 x 8 x 16 = 512 blocks
  invol_fused<<<grid, 256, 0, stream>>>(x, w_reduce, w_span, bn_gamma,
                                        bn_beta, bn_mean, bn_var, outp);
}